// Round 6
// baseline (287.966 us; speedup 1.0000x reference)
//
#include <hip/hip_runtime.h>
#include <hip/hip_bf16.h>
#include <math.h>

#define NNODES 100000
#define NEDGES 800000
#define HDIM 64
#define CDIM 10
#define NGRAPH 500
#define CAP 16                     // one 64B line per node bucket
#define OVFCAP 16384
#define BN_EPS 1e-5f
#define TN 64

__device__ __forceinline__ float bflo(unsigned u){ return __uint_as_float(u << 16); }
__device__ __forceinline__ float bfhi(unsigned u){ return __uint_as_float(u & 0xFFFF0000u); }
__device__ __forceinline__ unsigned f2bf(float f){
    unsigned u = __float_as_uint(f);
    u += 0x7FFFu + ((u >> 16) & 1u);          // RNE
    return u >> 16;
}

// ---------------- feat fp32 -> bf16 packed ------------------------------------------
__global__ void cvt_feat(const float4* __restrict__ F, uint4* __restrict__ B) {
    int i = blockIdx.x * 256 + threadIdx.x;   // exactly N*H/8 threads
    float4 a = F[2*i], b = F[2*i+1];
    uint4 o;
    o.x = f2bf(a.x) | (f2bf(a.y) << 16);
    o.y = f2bf(a.z) | (f2bf(a.w) << 16);
    o.z = f2bf(b.x) | (f2bf(b.y) << 16);
    o.w = f2bf(b.z) | (f2bf(b.w) << 16);
    B[i] = o;
}

// ---------------- bucketed CSR build (single kernel) --------------------------------
__global__ void fill_buckets(const int* __restrict__ src, const int* __restrict__ dst,
                             unsigned* __restrict__ cnt, int* __restrict__ csr,
                             unsigned* __restrict__ ovfcnt, int* __restrict__ ovf) {
    int e = blockIdx.x * blockDim.x + threadIdx.x;
    if (e >= NEDGES) return;
    int d = dst[e];
    unsigned slot = atomicAdd(&cnt[d], 1u);
    if (slot < CAP) {
        csr[(size_t)d * CAP + slot] = src[e];
    } else {
        unsigned o = atomicAdd(ovfcnt, 1u);
        if (o < OVFCAP) { ovf[2*o] = src[e]; ovf[2*o+1] = d; }
    }
}

// ------- fused layer: bf16 gather-aggregate into LDS, 64x64 GEMM + BN + ELU ---------
__global__ __launch_bounds__(256, 4) void layer_fused(
        const unsigned* __restrict__ hb, const unsigned* __restrict__ cnt,
        const int* __restrict__ csr, const unsigned* __restrict__ ovfcnt,
        const int* __restrict__ ovf,
        const float* __restrict__ Ws, const float* __restrict__ bs,
        const float* __restrict__ gammas, const float* __restrict__ betas,
        const float* __restrict__ means, const float* __restrict__ vars_,
        int layer, unsigned* __restrict__ outb) {
    __shared__ float Ml[TN][68];
    __shared__ float Wl[HDIM][68];
    int tid = threadIdx.x;

    // stage W (64x64 fp32), coalesced float4
    const float4* Wg4 = (const float4*)(Ws + (size_t)layer*HDIM*HDIM);
    #pragma unroll
    for (int r = 0; r < 4; ++r) {
        int f = tid + 256*r;
        int row = f >> 4, c4 = f & 15;
        *(float4*)&Wl[row][c4*4] = Wg4[f];
    }

    // aggregate: 8-lane group per node row, uint4 (8 bf16) per lane
    // static predicated unroll over CAP slots -> all gathers independent (deep MLP)
    int base = blockIdx.x * TN;
    int grp = tid >> 3;               // 0..31
    int sub = tid & 7;                // 16B column chunk
    const uint4* h4 = (const uint4*)hb;
    #pragma unroll
    for (int i = 0; i < 2; ++i) {
        int row = grp + 32*i;
        int node = base + row;
        float a0=0,a1=0,a2=0,a3=0,a4=0,a5=0,a6=0,a7=0;
        if (node < NNODES) {
            unsigned deg = cnt[node]; if (deg > CAP) deg = CAP;
            const int* ed = csr + (size_t)node * CAP;
            #pragma unroll
            for (int e = 0; e < CAP; ++e) {
                if ((unsigned)e < deg) {
                    uint4 v = h4[(size_t)ed[e]*8 + sub];
                    a0 += bflo(v.x); a1 += bfhi(v.x);
                    a2 += bflo(v.y); a3 += bfhi(v.y);
                    a4 += bflo(v.z); a5 += bfhi(v.z);
                    a6 += bflo(v.w); a7 += bfhi(v.w);
                }
            }
        }
        *(float4*)&Ml[row][sub*8]     = make_float4(a0,a1,a2,a3);
        *(float4*)&Ml[row][sub*8 + 4] = make_float4(a4,a5,a6,a7);
    }
    __syncthreads();

    // overflow edges (normally ~tens)
    unsigned novf = *ovfcnt; if (novf > OVFCAP) novf = OVFCAP;
    if (novf) {
        for (unsigned e = tid; e < novf; e += 256) {
            int s = ovf[2*e], d = ovf[2*e+1];
            if (d >= base && d < base + TN && d < NNODES) {
                const uint4* hr = h4 + (size_t)s*8;
                #pragma unroll
                for (int q = 0; q < 8; ++q) {
                    uint4 v = hr[q];
                    atomicAdd(&Ml[d-base][q*8+0], bflo(v.x));
                    atomicAdd(&Ml[d-base][q*8+1], bfhi(v.x));
                    atomicAdd(&Ml[d-base][q*8+2], bflo(v.y));
                    atomicAdd(&Ml[d-base][q*8+3], bfhi(v.y));
                    atomicAdd(&Ml[d-base][q*8+4], bflo(v.z));
                    atomicAdd(&Ml[d-base][q*8+5], bfhi(v.z));
                    atomicAdd(&Ml[d-base][q*8+6], bflo(v.w));
                    atomicAdd(&Ml[d-base][q*8+7], bfhi(v.w));
                }
            }
        }
        __syncthreads();
    }

    // GEMM phase: 4x4 per thread
    int tx = tid & 15;
    int ty = tid >> 4;
    float acc[4][4];
    #pragma unroll
    for (int i = 0; i < 4; ++i)
        #pragma unroll
        for (int j = 0; j < 4; ++j) acc[i][j] = 0.f;

    #pragma unroll 4
    for (int k4 = 0; k4 < 16; ++k4) {
        float4 b0 = *(const float4*)&Wl[4*k4+0][ty*4];
        float4 b1 = *(const float4*)&Wl[4*k4+1][ty*4];
        float4 b2 = *(const float4*)&Wl[4*k4+2][ty*4];
        float4 b3 = *(const float4*)&Wl[4*k4+3][ty*4];
        #pragma unroll
        for (int i = 0; i < 4; ++i) {
            float4 a = *(const float4*)&Ml[tx + 16*i][k4*4];
            acc[i][0] += a.x*b0.x + a.y*b1.x + a.z*b2.x + a.w*b3.x;
            acc[i][1] += a.x*b0.y + a.y*b1.y + a.z*b2.y + a.w*b3.y;
            acc[i][2] += a.x*b0.z + a.y*b1.z + a.z*b2.z + a.w*b3.z;
            acc[i][3] += a.x*b0.w + a.y*b1.w + a.z*b2.w + a.w*b3.w;
        }
    }

    // epilogue: BN folded scale/shift + ELU, pack bf16
    float sc[4], sh[4];
    #pragma unroll
    for (int j = 0; j < 4; ++j) {
        int c = ty*4 + j;
        float b  = bs[layer*HDIM + c];
        float gm = gammas[layer*HDIM + c];
        float be = betas[layer*HDIM + c];
        float mu = means[layer*HDIM + c];
        float vv = vars_[layer*HDIM + c];
        float s  = gm * rsqrtf(vv + BN_EPS);
        sc[j] = s;
        sh[j] = (b - mu) * s + be;
    }
    #pragma unroll
    for (int i = 0; i < 4; ++i) {
        int node = base + tx + 16*i;
        if (node >= NNODES) continue;
        float y0 = acc[i][0]*sc[0] + sh[0]; y0 = (y0 > 0.f) ? y0 : expm1f(y0);
        float y1 = acc[i][1]*sc[1] + sh[1]; y1 = (y1 > 0.f) ? y1 : expm1f(y1);
        float y2 = acc[i][2]*sc[2] + sh[2]; y2 = (y2 > 0.f) ? y2 : expm1f(y2);
        float y3 = acc[i][3]*sc[3] + sh[3]; y3 = (y3 > 0.f) ? y3 : expm1f(y3);
        uint2 o;
        o.x = f2bf(y0) | (f2bf(y1) << 16);
        o.y = f2bf(y2) | (f2bf(y3) << 16);
        *(uint2*)((unsigned*)outb + (size_t)node*32 + ty*2) = o;
    }
}

// ---------------- logits -> entropy per node (8 lanes/node) + block-max -------------
__global__ __launch_bounds__(256) void classify_bf16(
        const uint4* __restrict__ h4, const float* __restrict__ Wc,
        const float* __restrict__ bc, float* __restrict__ Hent,
        unsigned* __restrict__ maxH) {
    __shared__ float Wl[HDIM*11];     // stride 11: conflict-light
    __shared__ float bl[CDIM];
    __shared__ float wmax[4];
    int tid = threadIdx.x;
    for (int idx = tid; idx < HDIM*CDIM; idx += 256)
        Wl[(idx/CDIM)*11 + (idx%CDIM)] = Wc[idx];
    if (tid < CDIM) bl[tid] = bc[tid];
    __syncthreads();

    int node = blockIdx.x * 32 + (tid >> 3);
    int sub  = tid & 7;
    uint4 v = h4[(size_t)node*8 + sub];
    float h[8];
    h[0]=bflo(v.x); h[1]=bfhi(v.x); h[2]=bflo(v.y); h[3]=bfhi(v.y);
    h[4]=bflo(v.z); h[5]=bfhi(v.z); h[6]=bflo(v.w); h[7]=bfhi(v.w);

    float lg[CDIM];
    #pragma unroll
    for (int c = 0; c < CDIM; ++c) lg[c] = 0.f;
    #pragma unroll
    for (int k = 0; k < 8; ++k) {
        const float* wr = &Wl[(sub*8 + k)*11];
        float x = h[k];
        #pragma unroll
        for (int c = 0; c < CDIM; ++c) lg[c] += x * wr[c];
    }
    #pragma unroll
    for (int m = 1; m < 8; m <<= 1)
        #pragma unroll
        for (int c = 0; c < CDIM; ++c) lg[c] += __shfl_xor(lg[c], m, 64);
    #pragma unroll
    for (int c = 0; c < CDIM; ++c) lg[c] += bl[c];

    float mx = lg[0];
    #pragma unroll
    for (int c = 1; c < CDIM; ++c) mx = fmaxf(mx, lg[c]);
    float se = 0.f, dot = 0.f;
    #pragma unroll
    for (int c = 0; c < CDIM; ++c) { float e = expf(lg[c]-mx); se += e; dot += e*lg[c]; }
    float Hv = (mx + logf(se)) - dot/se;
    Hv = fmaxf(Hv, 0.f);
    if (sub == 0) Hent[node] = Hv;

    // block max -> 1 atomic
    float m8 = Hv;
    #pragma unroll
    for (int m = 8; m < 64; m <<= 1) m8 = fmaxf(m8, __shfl_xor(m8, m, 64));
    if ((tid & 63) == 0) wmax[tid >> 6] = m8;
    __syncthreads();
    if (tid == 0) {
        float mm = fmaxf(fmaxf(wmax[0], wmax[1]), fmaxf(wmax[2], wmax[3]));
        atomicMax(maxH, __float_as_uint(mm));
    }
}

// ---------------- per-graph lambda-weighted pooling + final classify ----------------
__global__ void pool_final_bf16(const unsigned* __restrict__ H2, const float* __restrict__ Hent,
                                const unsigned* __restrict__ maxH, const int* __restrict__ n2g,
                                const float* __restrict__ Wc, const float* __restrict__ bc,
                                float* __restrict__ out) {
    __shared__ float partial[8][HDIM];
    __shared__ float pooled[HDIM];
    int g = blockIdx.x;
    int tid = threadIdx.x;

    int lo = 0, hi = NNODES;
    while (lo < hi) { int mid = (lo+hi) >> 1; if (n2g[mid] < g) lo = mid+1; else hi = mid; }
    int start = lo;
    hi = NNODES;
    while (lo < hi) { int mid = (lo+hi) >> 1; if (n2g[mid] < g+1) lo = mid+1; else hi = mid; }
    int end = lo;

    float invMax = 1.0f / __uint_as_float(*maxH);
    int half = tid >> 5, l = tid & 31;
    float ax = 0.f, ay = 0.f;
    for (int i = start + half; i < end; i += 8) {
        float lam = 1.0f - Hent[i] * invMax;
        unsigned u = H2[(size_t)i*32 + l];
        ax += lam * bflo(u);
        ay += lam * bfhi(u);
    }
    partial[half][2*l]   = ax;
    partial[half][2*l+1] = ay;
    __syncthreads();
    if (tid < HDIM) {
        float s = 0.f;
        #pragma unroll
        for (int hh = 0; hh < 8; ++hh) s += partial[hh][tid];
        pooled[tid] = s;
    }
    __syncthreads();
    if (tid < CDIM) {
        float s = bc[tid];
        for (int k = 0; k < HDIM; ++k) s += pooled[k] * Wc[k*CDIM + tid];
        out[g*CDIM + tid] = s;
    }
}

extern "C" void kernel_launch(void* const* d_in, const int* in_sizes, int n_in,
                              void* d_out, int out_size, void* d_ws, size_t ws_size,
                              hipStream_t stream) {
    const float* feat  = (const float*)d_in[0];
    const int*   src   = (const int*)d_in[1];
    const int*   dst   = (const int*)d_in[2];
    const int*   n2g   = (const int*)d_in[3];
    const float* Ws    = (const float*)d_in[4];
    const float* bs    = (const float*)d_in[5];
    const float* gam   = (const float*)d_in[6];
    const float* bet   = (const float*)d_in[7];
    const float* mea   = (const float*)d_in[8];
    const float* var_  = (const float*)d_in[9];
    const float* Wc    = (const float*)d_in[10];
    const float* bc    = (const float*)d_in[11];
    float* out = (float*)d_out;

    char* ws = (char*)d_ws;
    size_t off = 0;
    auto take = [&](size_t bytes) {
        char* p = ws + off;
        off += (bytes + 255) & ~(size_t)255;
        return p;
    };

    unsigned* cnt    = (unsigned*)take((size_t)NNODES*4);
    unsigned* ovfcnt = (unsigned*)take(4);
    unsigned* maxH   = (unsigned*)take(4);
    int*      ovf    = (int*)take((size_t)OVFCAP*2*4);
    float*    Hent   = (float*)take((size_t)NNODES*4);
    unsigned* featb  = (unsigned*)take((size_t)NNODES*HDIM*2);
    unsigned* HA     = (unsigned*)take((size_t)NNODES*HDIM*2);
    unsigned* HB     = (unsigned*)take((size_t)NNODES*HDIM*2);
    int*      csr    = (int*)take((size_t)NNODES*CAP*4);

    hipMemsetAsync(cnt, 0, (size_t)NNODES*4, stream);
    hipMemsetAsync(ovfcnt, 0, 4, stream);
    hipMemsetAsync(maxH, 0, 4, stream);

    cvt_feat<<<(NNODES*HDIM/8 + 255)/256, 256, 0, stream>>>((const float4*)feat, (uint4*)featb);
    fill_buckets<<<(NEDGES+255)/256, 256, 0, stream>>>(src, dst, cnt, csr, ovfcnt, ovf);

    int grid = (NNODES + TN - 1) / TN;
    layer_fused<<<grid, 256, 0, stream>>>(featb, cnt, csr, ovfcnt, ovf,
                                          Ws, bs, gam, bet, mea, var_, 0, HA);
    layer_fused<<<grid, 256, 0, stream>>>(HA, cnt, csr, ovfcnt, ovf,
                                          Ws, bs, gam, bet, mea, var_, 1, HB);
    layer_fused<<<grid, 256, 0, stream>>>(HB, cnt, csr, ovfcnt, ovf,
                                          Ws, bs, gam, bet, mea, var_, 2, HA);

    classify_bf16<<<(NNODES+31)/32, 256, 0, stream>>>((const uint4*)HA, Wc, bc, Hent, maxH);
    pool_final_bf16<<<NGRAPH, 256, 0, stream>>>(HA, Hent, maxH, n2g, Wc, bc, out);
}

// Round 7
// 196.181 us; speedup vs baseline: 1.4679x; 1.4679x over previous
//
#include <hip/hip_runtime.h>
#include <hip/hip_bf16.h>
#include <math.h>

#define NNODES 100000
#define NEDGES 800000
#define HDIM 64
#define CDIM 10
#define NGRAPH 500
#define CAP 24
#define OVFCAP 16384
#define BN_EPS 1e-5f
#define TN 64

typedef __attribute__((ext_vector_type(8))) short short8;
typedef __attribute__((ext_vector_type(4))) float f32x4;

__device__ __forceinline__ float bflo(unsigned u){ return __uint_as_float(u << 16); }
__device__ __forceinline__ float bfhi(unsigned u){ return __uint_as_float(u & 0xFFFF0000u); }
__device__ __forceinline__ unsigned f2bf(float f){
    unsigned u = __float_as_uint(f);
    u += 0x7FFFu + ((u >> 16) & 1u);          // RNE
    return u >> 16;
}

// ---------------- feat fp32 -> bf16 packed ------------------------------------------
__global__ void cvt_feat(const float4* __restrict__ F, uint4* __restrict__ B) {
    int i = blockIdx.x * 256 + threadIdx.x;   // exactly N*H/8 threads
    float4 a = F[2*i], b = F[2*i+1];
    uint4 o;
    o.x = f2bf(a.x) | (f2bf(a.y) << 16);
    o.y = f2bf(a.z) | (f2bf(a.w) << 16);
    o.z = f2bf(b.x) | (f2bf(b.y) << 16);
    o.w = f2bf(b.z) | (f2bf(b.w) << 16);
    B[i] = o;
}

// ---------------- bucketed CSR build (single kernel) --------------------------------
__global__ void fill_buckets(const int* __restrict__ src, const int* __restrict__ dst,
                             unsigned* __restrict__ cnt, int* __restrict__ csr,
                             unsigned* __restrict__ ovfcnt, int* __restrict__ ovf) {
    int e = blockIdx.x * blockDim.x + threadIdx.x;
    if (e >= NEDGES) return;
    int d = dst[e];
    unsigned slot = atomicAdd(&cnt[d], 1u);
    if (slot < CAP) {
        csr[(size_t)d * CAP + slot] = src[e];
    } else {
        unsigned o = atomicAdd(ovfcnt, 1u);
        if (o < OVFCAP) { ovf[2*o] = src[e]; ovf[2*o+1] = d; }
    }
}

// ------ fused layer: bf16 gather -> bf16 LDS -> MFMA 64x64 GEMM + BN + ELU ----------
__global__ __launch_bounds__(256, 6) void layer_fused(
        const unsigned* __restrict__ hb, const unsigned* __restrict__ cnt,
        const int* __restrict__ csr, const unsigned* __restrict__ ovfcnt,
        const int* __restrict__ ovf,
        const float* __restrict__ Ws, const float* __restrict__ bs,
        const float* __restrict__ gammas, const float* __restrict__ betas,
        const float* __restrict__ means, const float* __restrict__ vars_,
        int layer, unsigned short* __restrict__ out16) {
    __shared__ unsigned short Mb[TN][72];     // node x k, bf16, stride 72 (2-way alias only)
    __shared__ unsigned short Wt[HDIM][72];   // W^T: col x k, bf16
    __shared__ float Scl[HDIM], Shl[HDIM];
    int tid = threadIdx.x;
    int base = blockIdx.x * TN;

    // stage W^T (transpose during store) : 4096 elems, 16 per thread
    const float* Wg = Ws + (size_t)layer*HDIM*HDIM;
    #pragma unroll
    for (int r = 0; r < 16; ++r) {
        int f = tid + 256*r;                  // f = k*64 + c
        int k = f >> 6, c = f & 63;
        Wt[c][k] = (unsigned short)f2bf(Wg[f]);
    }
    // BN folded scale/shift per column
    if (tid < HDIM) {
        int c = tid;
        float b  = bs[layer*HDIM + c];
        float gm = gammas[layer*HDIM + c];
        float be = betas[layer*HDIM + c];
        float mu = means[layer*HDIM + c];
        float vv = vars_[layer*HDIM + c];
        float s  = gm * rsqrtf(vv + BN_EPS);
        Scl[c] = s;
        Shl[c] = (b - mu) * s + be;
    }

    // aggregate: 8-lane group per node row, uint4 (8 bf16) per lane; fp32 accum in regs
    int grp = tid >> 3;               // 0..31
    int sub = tid & 7;                // 16B column chunk
    const uint4* h4 = (const uint4*)hb;
    unsigned novf = *ovfcnt; if (novf > OVFCAP) novf = OVFCAP;
    #pragma unroll
    for (int i = 0; i < 2; ++i) {
        int row = grp + 32*i;
        int node = base + row;
        float a0=0,a1=0,a2=0,a3=0,a4=0,a5=0,a6=0,a7=0;
        if (node < NNODES) {
            unsigned deg = cnt[node]; if (deg > CAP) deg = CAP;
            const int* ed = csr + (size_t)node * CAP;
            unsigned e = 0;
            for (; e + 4 <= deg; e += 4) {
                int s0 = ed[e], s1 = ed[e+1], s2 = ed[e+2], s3 = ed[e+3];
                uint4 v0 = h4[(size_t)s0*8 + sub];
                uint4 v1 = h4[(size_t)s1*8 + sub];
                uint4 v2 = h4[(size_t)s2*8 + sub];
                uint4 v3 = h4[(size_t)s3*8 + sub];
                a0 += bflo(v0.x)+bflo(v1.x)+bflo(v2.x)+bflo(v3.x);
                a1 += bfhi(v0.x)+bfhi(v1.x)+bfhi(v2.x)+bfhi(v3.x);
                a2 += bflo(v0.y)+bflo(v1.y)+bflo(v2.y)+bflo(v3.y);
                a3 += bfhi(v0.y)+bfhi(v1.y)+bfhi(v2.y)+bfhi(v3.y);
                a4 += bflo(v0.z)+bflo(v1.z)+bflo(v2.z)+bflo(v3.z);
                a5 += bfhi(v0.z)+bfhi(v1.z)+bfhi(v2.z)+bfhi(v3.z);
                a6 += bflo(v0.w)+bflo(v1.w)+bflo(v2.w)+bflo(v3.w);
                a7 += bfhi(v0.w)+bfhi(v1.w)+bfhi(v2.w)+bfhi(v3.w);
            }
            for (; e < deg; ++e) {
                uint4 v = h4[(size_t)ed[e]*8 + sub];
                a0 += bflo(v.x); a1 += bfhi(v.x);
                a2 += bflo(v.y); a3 += bfhi(v.y);
                a4 += bflo(v.z); a5 += bfhi(v.z);
                a6 += bflo(v.w); a7 += bfhi(v.w);
            }
            // rare overflow edges for this node (expected 0 at CAP=24)
            if (novf) {
                for (unsigned o = 0; o < novf; ++o) {
                    if (ovf[2*o+1] == node) {
                        uint4 v = h4[(size_t)ovf[2*o]*8 + sub];
                        a0 += bflo(v.x); a1 += bfhi(v.x);
                        a2 += bflo(v.y); a3 += bfhi(v.y);
                        a4 += bflo(v.z); a5 += bfhi(v.z);
                        a6 += bflo(v.w); a7 += bfhi(v.w);
                    }
                }
            }
        }
        uint4 p;
        p.x = f2bf(a0) | (f2bf(a1) << 16);
        p.y = f2bf(a2) | (f2bf(a3) << 16);
        p.z = f2bf(a4) | (f2bf(a5) << 16);
        p.w = f2bf(a6) | (f2bf(a7) << 16);
        *(uint4*)&Mb[row][sub*8] = p;
    }
    __syncthreads();

    // MFMA GEMM: wave w -> node rows w*16..w*16+15, all 64 cols (4 tiles), K=64
    int w  = tid >> 6;
    int l  = tid & 63;
    int lr = l & 15;                  // A row / B col within tile
    int lq = l >> 4;                  // k-chunk selector
    short8 a0 = *(const short8*)&Mb[w*16 + lr][lq*8];
    short8 a1 = *(const short8*)&Mb[w*16 + lr][32 + lq*8];
    f32x4 acc0 = {0.f,0.f,0.f,0.f}, acc1 = acc0, acc2 = acc0, acc3 = acc0;
    {
        short8 b0 = *(const short8*)&Wt[ 0 + lr][lq*8];
        short8 b1 = *(const short8*)&Wt[ 0 + lr][32 + lq*8];
        acc0 = __builtin_amdgcn_mfma_f32_16x16x32_bf16(a0, b0, acc0, 0, 0, 0);
        acc0 = __builtin_amdgcn_mfma_f32_16x16x32_bf16(a1, b1, acc0, 0, 0, 0);
    }
    {
        short8 b0 = *(const short8*)&Wt[16 + lr][lq*8];
        short8 b1 = *(const short8*)&Wt[16 + lr][32 + lq*8];
        acc1 = __builtin_amdgcn_mfma_f32_16x16x32_bf16(a0, b0, acc1, 0, 0, 0);
        acc1 = __builtin_amdgcn_mfma_f32_16x16x32_bf16(a1, b1, acc1, 0, 0, 0);
    }
    {
        short8 b0 = *(const short8*)&Wt[32 + lr][lq*8];
        short8 b1 = *(const short8*)&Wt[32 + lr][32 + lq*8];
        acc2 = __builtin_amdgcn_mfma_f32_16x16x32_bf16(a0, b0, acc2, 0, 0, 0);
        acc2 = __builtin_amdgcn_mfma_f32_16x16x32_bf16(a1, b1, acc2, 0, 0, 0);
    }
    {
        short8 b0 = *(const short8*)&Wt[48 + lr][lq*8];
        short8 b1 = *(const short8*)&Wt[48 + lr][32 + lq*8];
        acc3 = __builtin_amdgcn_mfma_f32_16x16x32_bf16(a0, b0, acc3, 0, 0, 0);
        acc3 = __builtin_amdgcn_mfma_f32_16x16x32_bf16(a1, b1, acc3, 0, 0, 0);
    }

    // epilogue: BN + ELU, store bf16. C layout: col=lane&15, row=(lane>>4)*4+reg
    #pragma unroll
    for (int t = 0; t < 4; ++t) {
        f32x4 a = (t==0)?acc0:(t==1)?acc1:(t==2)?acc2:acc3;
        int col = t*16 + lr;
        float s = Scl[col], sh = Shl[col];
        #pragma unroll
        for (int r = 0; r < 4; ++r) {
            int node = base + w*16 + lq*4 + r;
            if (node < NNODES) {
                float y = a[r]*s + sh;
                y = (y > 0.f) ? y : expm1f(y);
                out16[(size_t)node*HDIM + col] = (unsigned short)f2bf(y);
            }
        }
    }
}

// ---------------- logits -> entropy per node (8 lanes/node) + block-max -------------
__global__ __launch_bounds__(256) void classify_bf16(
        const uint4* __restrict__ h4, const float* __restrict__ Wc,
        const float* __restrict__ bc, float* __restrict__ Hent,
        unsigned* __restrict__ maxH) {
    __shared__ float Wl[HDIM*11];     // stride 11: conflict-light
    __shared__ float bl[CDIM];
    __shared__ float wmax[4];
    int tid = threadIdx.x;
    for (int idx = tid; idx < HDIM*CDIM; idx += 256)
        Wl[(idx/CDIM)*11 + (idx%CDIM)] = Wc[idx];
    if (tid < CDIM) bl[tid] = bc[tid];
    __syncthreads();

    int node = blockIdx.x * 32 + (tid >> 3);
    int sub  = tid & 7;
    uint4 v = h4[(size_t)node*8 + sub];
    float h[8];
    h[0]=bflo(v.x); h[1]=bfhi(v.x); h[2]=bflo(v.y); h[3]=bfhi(v.y);
    h[4]=bflo(v.z); h[5]=bfhi(v.z); h[6]=bflo(v.w); h[7]=bfhi(v.w);

    float lg[CDIM];
    #pragma unroll
    for (int c = 0; c < CDIM; ++c) lg[c] = 0.f;
    #pragma unroll
    for (int k = 0; k < 8; ++k) {
        const float* wr = &Wl[(sub*8 + k)*11];
        float x = h[k];
        #pragma unroll
        for (int c = 0; c < CDIM; ++c) lg[c] += x * wr[c];
    }
    #pragma unroll
    for (int m = 1; m < 8; m <<= 1)
        #pragma unroll
        for (int c = 0; c < CDIM; ++c) lg[c] += __shfl_xor(lg[c], m, 64);
    #pragma unroll
    for (int c = 0; c < CDIM; ++c) lg[c] += bl[c];

    float mx = lg[0];
    #pragma unroll
    for (int c = 1; c < CDIM; ++c) mx = fmaxf(mx, lg[c]);
    float se = 0.f, dot = 0.f;
    #pragma unroll
    for (int c = 0; c < CDIM; ++c) { float e = expf(lg[c]-mx); se += e; dot += e*lg[c]; }
    float Hv = (mx + logf(se)) - dot/se;
    Hv = fmaxf(Hv, 0.f);
    if (sub == 0) Hent[node] = Hv;

    float m8 = Hv;
    #pragma unroll
    for (int m = 8; m < 64; m <<= 1) m8 = fmaxf(m8, __shfl_xor(m8, m, 64));
    if ((tid & 63) == 0) wmax[tid >> 6] = m8;
    __syncthreads();
    if (tid == 0) {
        float mm = fmaxf(fmaxf(wmax[0], wmax[1]), fmaxf(wmax[2], wmax[3]));
        atomicMax(maxH, __float_as_uint(mm));
    }
}

// ---------------- per-graph lambda-weighted pooling + final classify ----------------
__global__ void pool_final_bf16(const unsigned* __restrict__ H2, const float* __restrict__ Hent,
                                const unsigned* __restrict__ maxH, const int* __restrict__ n2g,
                                const float* __restrict__ Wc, const float* __restrict__ bc,
                                float* __restrict__ out) {
    __shared__ float partial[8][HDIM];
    __shared__ float pooled[HDIM];
    int g = blockIdx.x;
    int tid = threadIdx.x;

    int lo = 0, hi = NNODES;
    while (lo < hi) { int mid = (lo+hi) >> 1; if (n2g[mid] < g) lo = mid+1; else hi = mid; }
    int start = lo;
    hi = NNODES;
    while (lo < hi) { int mid = (lo+hi) >> 1; if (n2g[mid] < g+1) lo = mid+1; else hi = mid; }
    int end = lo;

    float invMax = 1.0f / __uint_as_float(*maxH);
    int half = tid >> 5, l = tid & 31;
    float ax = 0.f, ay = 0.f;
    for (int i = start + half; i < end; i += 8) {
        float lam = 1.0f - Hent[i] * invMax;
        unsigned u = H2[(size_t)i*32 + l];
        ax += lam * bflo(u);
        ay += lam * bfhi(u);
    }
    partial[half][2*l]   = ax;
    partial[half][2*l+1] = ay;
    __syncthreads();
    if (tid < HDIM) {
        float s = 0.f;
        #pragma unroll
        for (int hh = 0; hh < 8; ++hh) s += partial[hh][tid];
        pooled[tid] = s;
    }
    __syncthreads();
    if (tid < CDIM) {
        float s = bc[tid];
        for (int k = 0; k < HDIM; ++k) s += pooled[k] * Wc[k*CDIM + tid];
        out[g*CDIM + tid] = s;
    }
}

extern "C" void kernel_launch(void* const* d_in, const int* in_sizes, int n_in,
                              void* d_out, int out_size, void* d_ws, size_t ws_size,
                              hipStream_t stream) {
    const float* feat  = (const float*)d_in[0];
    const int*   src   = (const int*)d_in[1];
    const int*   dst   = (const int*)d_in[2];
    const int*   n2g   = (const int*)d_in[3];
    const float* Ws    = (const float*)d_in[4];
    const float* bs    = (const float*)d_in[5];
    const float* gam   = (const float*)d_in[6];
    const float* bet   = (const float*)d_in[7];
    const float* mea   = (const float*)d_in[8];
    const float* var_  = (const float*)d_in[9];
    const float* Wc    = (const float*)d_in[10];
    const float* bc    = (const float*)d_in[11];
    float* out = (float*)d_out;

    char* ws = (char*)d_ws;
    size_t off = 0;
    auto take = [&](size_t bytes) {
        char* p = ws + off;
        off += (bytes + 255) & ~(size_t)255;
        return p;
    };

    unsigned* cnt    = (unsigned*)take((size_t)NNODES*4);
    unsigned* ovfcnt = (unsigned*)take(4);
    unsigned* maxH   = (unsigned*)take(4);
    int*      ovf    = (int*)take((size_t)OVFCAP*2*4);
    float*    Hent   = (float*)take((size_t)NNODES*4);
    unsigned* featb  = (unsigned*)take((size_t)NNODES*HDIM*2);
    unsigned* HA     = (unsigned*)take((size_t)NNODES*HDIM*2);
    unsigned* HB     = (unsigned*)take((size_t)NNODES*HDIM*2);
    int*      csr    = (int*)take((size_t)NNODES*CAP*4);

    hipMemsetAsync(cnt, 0, (size_t)NNODES*4, stream);
    hipMemsetAsync(ovfcnt, 0, 4, stream);
    hipMemsetAsync(maxH, 0, 4, stream);

    cvt_feat<<<(NNODES*HDIM/8 + 255)/256, 256, 0, stream>>>((const float4*)feat, (uint4*)featb);
    fill_buckets<<<(NEDGES+255)/256, 256, 0, stream>>>(src, dst, cnt, csr, ovfcnt, ovf);

    int grid = (NNODES + TN - 1) / TN;
    layer_fused<<<grid, 256, 0, stream>>>(featb, cnt, csr, ovfcnt, ovf,
                                          Ws, bs, gam, bet, mea, var_, 0, (unsigned short*)HA);
    layer_fused<<<grid, 256, 0, stream>>>((const unsigned*)HA, cnt, csr, ovfcnt, ovf,
                                          Ws, bs, gam, bet, mea, var_, 1, (unsigned short*)HB);
    layer_fused<<<grid, 256, 0, stream>>>((const unsigned*)HB, cnt, csr, ovfcnt, ovf,
                                          Ws, bs, gam, bet, mea, var_, 2, (unsigned short*)HA);

    classify_bf16<<<(NNODES+31)/32, 256, 0, stream>>>((const uint4*)HA, Wc, bc, Hent, maxH);
    pool_final_bf16<<<NGRAPH, 256, 0, stream>>>(HA, Hent, maxH, n2g, Wc, bc, out);
}

// Round 8
// 194.031 us; speedup vs baseline: 1.4841x; 1.0111x over previous
//
#include <hip/hip_runtime.h>
#include <hip/hip_bf16.h>
#include <math.h>

#define NNODES 100000
#define NEDGES 800000
#define HDIM 64
#define CDIM 10
#define NGRAPH 500
#define CAP 24
#define OVFCAP 16384
#define BN_EPS 1e-5f
#define TN 64
#define NBINS 782                 // ceil(100000/128)
#define BINCAP 2048               // mean 1023, sd 32 -> 32 sigma headroom
#define GCUR_STRIDE 16            // one 64B line per bin counter

typedef __attribute__((ext_vector_type(8))) short short8;
typedef __attribute__((ext_vector_type(4))) float f32x4;

__device__ __forceinline__ float bflo(unsigned u){ return __uint_as_float(u << 16); }
__device__ __forceinline__ float bfhi(unsigned u){ return __uint_as_float(u & 0xFFFF0000u); }
__device__ __forceinline__ unsigned f2bf(float f){
    unsigned u = __float_as_uint(f);
    u += 0x7FFFu + ((u >> 16) & 1u);          // RNE
    return u >> 16;
}

// ------- prep: feat fp32->bf16 (same 800K items) + edge partition by dst/128 --------
__global__ void prep(const float4* __restrict__ F, uint4* __restrict__ B,
                     const int* __restrict__ src, const int* __restrict__ dst,
                     unsigned* __restrict__ gcur, unsigned* __restrict__ bin_edges,
                     unsigned* __restrict__ ovfcnt, int* __restrict__ ovf) {
    int i = blockIdx.x * 256 + threadIdx.x;   // exactly NEDGES == N*H/8 items
    // feature convert (bf16 pack)
    float4 a = F[2*i], b = F[2*i+1];
    uint4 o;
    o.x = f2bf(a.x) | (f2bf(a.y) << 16);
    o.y = f2bf(a.z) | (f2bf(a.w) << 16);
    o.z = f2bf(b.x) | (f2bf(b.y) << 16);
    o.w = f2bf(b.z) | (f2bf(b.w) << 16);
    B[i] = o;
    // edge partition: append packed (ln,src) at bin frontier
    int d = dst[i], s = src[i];
    int bin = d >> 7;
    unsigned pos = atomicAdd(&gcur[bin * GCUR_STRIDE], 1u);
    unsigned u = ((unsigned)(d & 127) << 24) | (unsigned)s;
    if (pos < BINCAP) bin_edges[(size_t)bin * BINCAP + pos] = u;
    else { unsigned oo = atomicAdd(ovfcnt, 1u);
           if (oo < OVFCAP) { ovf[2*oo] = s; ovf[2*oo+1] = d; } }
}

// ------- build_csr: one block per 128-node bin, LDS-local build, streaming out ------
__global__ __launch_bounds__(256) void build_csr(
        const unsigned* __restrict__ gcur, const unsigned* __restrict__ bin_edges,
        unsigned* __restrict__ cnt, int* __restrict__ csr,
        unsigned* __restrict__ ovfcnt, int* __restrict__ ovf) {
    __shared__ unsigned lcnt[128];
    __shared__ __align__(16) int lcsr[128][CAP];
    int p = blockIdx.x, tid = threadIdx.x;
    if (tid < 128) lcnt[tid] = 0;
    __syncthreads();
    unsigned ecnt = gcur[p * GCUR_STRIDE]; if (ecnt > BINCAP) ecnt = BINCAP;
    for (unsigned i = tid; i < ecnt; i += 256) {
        unsigned u = bin_edges[(size_t)p * BINCAP + i];
        unsigned ln = u >> 24; int s = (int)(u & 0xFFFFFFu);
        unsigned slot = atomicAdd(&lcnt[ln], 1u);
        if (slot < CAP) lcsr[ln][slot] = s;
        else {
            unsigned oo = atomicAdd(ovfcnt, 1u);
            if (oo < OVFCAP) { ovf[2*oo] = s; ovf[2*oo+1] = (p << 7) + (int)ln; }
        }
    }
    __syncthreads();
    int node = (p << 7) + tid;
    if (tid < 128 && node < NNODES) cnt[node] = lcnt[tid];
    const uint4* ls = (const uint4*)&lcsr[0][0];
    uint4* gs = (uint4*)(csr + (size_t)(p << 7) * CAP);   // 12KB contiguous
    #pragma unroll
    for (int i = tid; i < 128*CAP/4; i += 256) gs[i] = ls[i];
}

// ------ fused layer: bf16 gather -> bf16 LDS -> MFMA 64x64 GEMM + BN + ELU ----------
__global__ __launch_bounds__(256, 8) void layer_fused(
        const unsigned* __restrict__ hb, const unsigned* __restrict__ cnt,
        const int* __restrict__ csr, const unsigned* __restrict__ ovfcnt,
        const int* __restrict__ ovf,
        const float* __restrict__ Ws, const float* __restrict__ bs,
        const float* __restrict__ gammas, const float* __restrict__ betas,
        const float* __restrict__ means, const float* __restrict__ vars_,
        int layer, unsigned short* __restrict__ out16) {
    __shared__ unsigned short Mb[TN][72];     // node x k, bf16
    __shared__ unsigned short Wt[HDIM][72];   // W^T: col x k, bf16
    __shared__ float Scl[HDIM], Shl[HDIM];
    int tid = threadIdx.x;
    int base = blockIdx.x * TN;

    // stage W^T (transpose during store)
    const float* Wg = Ws + (size_t)layer*HDIM*HDIM;
    #pragma unroll
    for (int r = 0; r < 16; ++r) {
        int f = tid + 256*r;                  // f = k*64 + c
        int k = f >> 6, c = f & 63;
        Wt[c][k] = (unsigned short)f2bf(Wg[f]);
    }
    if (tid < HDIM) {
        int c = tid;
        float b  = bs[layer*HDIM + c];
        float gm = gammas[layer*HDIM + c];
        float be = betas[layer*HDIM + c];
        float mu = means[layer*HDIM + c];
        float vv = vars_[layer*HDIM + c];
        float s  = gm * rsqrtf(vv + BN_EPS);
        Scl[c] = s;
        Shl[c] = (b - mu) * s + be;
    }

    // aggregate: 8-lane group per node row, uint4 (8 bf16) per lane; fp32 accum
    int grp = tid >> 3;
    int sub = tid & 7;
    const uint4* h4 = (const uint4*)hb;
    unsigned novf = *ovfcnt; if (novf > OVFCAP) novf = OVFCAP;
    #pragma unroll
    for (int i = 0; i < 2; ++i) {
        int row = grp + 32*i;
        int node = base + row;
        float a0=0,a1=0,a2=0,a3=0,a4=0,a5=0,a6=0,a7=0;
        if (node < NNODES) {
            unsigned deg = cnt[node]; if (deg > CAP) deg = CAP;
            const int* ed = csr + (size_t)node * CAP;
            unsigned e = 0;
            for (; e + 4 <= deg; e += 4) {
                int s0 = ed[e], s1 = ed[e+1], s2 = ed[e+2], s3 = ed[e+3];
                uint4 v0 = h4[(size_t)s0*8 + sub];
                uint4 v1 = h4[(size_t)s1*8 + sub];
                uint4 v2 = h4[(size_t)s2*8 + sub];
                uint4 v3 = h4[(size_t)s3*8 + sub];
                a0 += bflo(v0.x)+bflo(v1.x)+bflo(v2.x)+bflo(v3.x);
                a1 += bfhi(v0.x)+bfhi(v1.x)+bfhi(v2.x)+bfhi(v3.x);
                a2 += bflo(v0.y)+bflo(v1.y)+bflo(v2.y)+bflo(v3.y);
                a3 += bfhi(v0.y)+bfhi(v1.y)+bfhi(v2.y)+bfhi(v3.y);
                a4 += bflo(v0.z)+bflo(v1.z)+bflo(v2.z)+bflo(v3.z);
                a5 += bfhi(v0.z)+bfhi(v1.z)+bfhi(v2.z)+bfhi(v3.z);
                a6 += bflo(v0.w)+bflo(v1.w)+bflo(v2.w)+bflo(v3.w);
                a7 += bfhi(v0.w)+bfhi(v1.w)+bfhi(v2.w)+bfhi(v3.w);
            }
            for (; e < deg; ++e) {
                uint4 v = h4[(size_t)ed[e]*8 + sub];
                a0 += bflo(v.x); a1 += bfhi(v.x);
                a2 += bflo(v.y); a3 += bfhi(v.y);
                a4 += bflo(v.z); a5 += bfhi(v.z);
                a6 += bflo(v.w); a7 += bfhi(v.w);
            }
            if (novf) {
                for (unsigned o = 0; o < novf; ++o) {
                    if (ovf[2*o+1] == node) {
                        uint4 v = h4[(size_t)ovf[2*o]*8 + sub];
                        a0 += bflo(v.x); a1 += bfhi(v.x);
                        a2 += bflo(v.y); a3 += bfhi(v.y);
                        a4 += bflo(v.z); a5 += bfhi(v.z);
                        a6 += bflo(v.w); a7 += bfhi(v.w);
                    }
                }
            }
        }
        uint4 pk;
        pk.x = f2bf(a0) | (f2bf(a1) << 16);
        pk.y = f2bf(a2) | (f2bf(a3) << 16);
        pk.z = f2bf(a4) | (f2bf(a5) << 16);
        pk.w = f2bf(a6) | (f2bf(a7) << 16);
        *(uint4*)&Mb[row][sub*8] = pk;
    }
    __syncthreads();

    // MFMA GEMM: wave w -> rows w*16..+15, 4 col tiles, K=64
    int w  = tid >> 6;
    int l  = tid & 63;
    int lr = l & 15;
    int lq = l >> 4;
    short8 a0 = *(const short8*)&Mb[w*16 + lr][lq*8];
    short8 a1 = *(const short8*)&Mb[w*16 + lr][32 + lq*8];
    f32x4 acc0 = {0.f,0.f,0.f,0.f}, acc1 = acc0, acc2 = acc0, acc3 = acc0;
    {
        short8 b0 = *(const short8*)&Wt[ 0 + lr][lq*8];
        short8 b1 = *(const short8*)&Wt[ 0 + lr][32 + lq*8];
        acc0 = __builtin_amdgcn_mfma_f32_16x16x32_bf16(a0, b0, acc0, 0, 0, 0);
        acc0 = __builtin_amdgcn_mfma_f32_16x16x32_bf16(a1, b1, acc0, 0, 0, 0);
    }
    {
        short8 b0 = *(const short8*)&Wt[16 + lr][lq*8];
        short8 b1 = *(const short8*)&Wt[16 + lr][32 + lq*8];
        acc1 = __builtin_amdgcn_mfma_f32_16x16x32_bf16(a0, b0, acc1, 0, 0, 0);
        acc1 = __builtin_amdgcn_mfma_f32_16x16x32_bf16(a1, b1, acc1, 0, 0, 0);
    }
    {
        short8 b0 = *(const short8*)&Wt[32 + lr][lq*8];
        short8 b1 = *(const short8*)&Wt[32 + lr][32 + lq*8];
        acc2 = __builtin_amdgcn_mfma_f32_16x16x32_bf16(a0, b0, acc2, 0, 0, 0);
        acc2 = __builtin_amdgcn_mfma_f32_16x16x32_bf16(a1, b1, acc2, 0, 0, 0);
    }
    {
        short8 b0 = *(const short8*)&Wt[48 + lr][lq*8];
        short8 b1 = *(const short8*)&Wt[48 + lr][32 + lq*8];
        acc3 = __builtin_amdgcn_mfma_f32_16x16x32_bf16(a0, b0, acc3, 0, 0, 0);
        acc3 = __builtin_amdgcn_mfma_f32_16x16x32_bf16(a1, b1, acc3, 0, 0, 0);
    }

    // epilogue: BN + ELU, store bf16. C layout: col=lane&15, row=(lane>>4)*4+reg
    #pragma unroll
    for (int t = 0; t < 4; ++t) {
        f32x4 a = (t==0)?acc0:(t==1)?acc1:(t==2)?acc2:acc3;
        int col = t*16 + lr;
        float s = Scl[col], sh = Shl[col];
        #pragma unroll
        for (int r = 0; r < 4; ++r) {
            int node = base + w*16 + lq*4 + r;
            if (node < NNODES) {
                float y = a[r]*s + sh;
                y = (y > 0.f) ? y : expm1f(y);
                out16[(size_t)node*HDIM + col] = (unsigned short)f2bf(y);
            }
        }
    }
}

// ---------------- logits -> entropy per node (8 lanes/node) + block-max -------------
__global__ __launch_bounds__(256) void classify_bf16(
        const uint4* __restrict__ h4, const float* __restrict__ Wc,
        const float* __restrict__ bc, float* __restrict__ Hent,
        unsigned* __restrict__ maxH) {
    __shared__ float Wl[HDIM*11];
    __shared__ float bl[CDIM];
    __shared__ float wmax[4];
    int tid = threadIdx.x;
    for (int idx = tid; idx < HDIM*CDIM; idx += 256)
        Wl[(idx/CDIM)*11 + (idx%CDIM)] = Wc[idx];
    if (tid < CDIM) bl[tid] = bc[tid];
    __syncthreads();

    int node = blockIdx.x * 32 + (tid >> 3);
    int sub  = tid & 7;
    uint4 v = h4[(size_t)node*8 + sub];
    float h[8];
    h[0]=bflo(v.x); h[1]=bfhi(v.x); h[2]=bflo(v.y); h[3]=bfhi(v.y);
    h[4]=bflo(v.z); h[5]=bfhi(v.z); h[6]=bflo(v.w); h[7]=bfhi(v.w);

    float lg[CDIM];
    #pragma unroll
    for (int c = 0; c < CDIM; ++c) lg[c] = 0.f;
    #pragma unroll
    for (int k = 0; k < 8; ++k) {
        const float* wr = &Wl[(sub*8 + k)*11];
        float x = h[k];
        #pragma unroll
        for (int c = 0; c < CDIM; ++c) lg[c] += x * wr[c];
    }
    #pragma unroll
    for (int m = 1; m < 8; m <<= 1)
        #pragma unroll
        for (int c = 0; c < CDIM; ++c) lg[c] += __shfl_xor(lg[c], m, 64);
    #pragma unroll
    for (int c = 0; c < CDIM; ++c) lg[c] += bl[c];

    float mx = lg[0];
    #pragma unroll
    for (int c = 1; c < CDIM; ++c) mx = fmaxf(mx, lg[c]);
    float se = 0.f, dot = 0.f;
    #pragma unroll
    for (int c = 0; c < CDIM; ++c) { float e = expf(lg[c]-mx); se += e; dot += e*lg[c]; }
    float Hv = (mx + logf(se)) - dot/se;
    Hv = fmaxf(Hv, 0.f);
    if (sub == 0) Hent[node] = Hv;

    float m8 = Hv;
    #pragma unroll
    for (int m = 8; m < 64; m <<= 1) m8 = fmaxf(m8, __shfl_xor(m8, m, 64));
    if ((tid & 63) == 0) wmax[tid >> 6] = m8;
    __syncthreads();
    if (tid == 0) {
        float mm = fmaxf(fmaxf(wmax[0], wmax[1]), fmaxf(wmax[2], wmax[3]));
        atomicMax(maxH, __float_as_uint(mm));
    }
}

// ---------------- per-graph lambda-weighted pooling + final classify ----------------
__global__ void pool_final_bf16(const unsigned* __restrict__ H2, const float* __restrict__ Hent,
                                const unsigned* __restrict__ maxH, const int* __restrict__ n2g,
                                const float* __restrict__ Wc, const float* __restrict__ bc,
                                float* __restrict__ out) {
    __shared__ float partial[8][HDIM];
    __shared__ float pooled[HDIM];
    int g = blockIdx.x;
    int tid = threadIdx.x;

    int lo = 0, hi = NNODES;
    while (lo < hi) { int mid = (lo+hi) >> 1; if (n2g[mid] < g) lo = mid+1; else hi = mid; }
    int start = lo;
    hi = NNODES;
    while (lo < hi) { int mid = (lo+hi) >> 1; if (n2g[mid] < g+1) lo = mid+1; else hi = mid; }
    int end = lo;

    float invMax = 1.0f / __uint_as_float(*maxH);
    int half = tid >> 5, l = tid & 31;
    float ax = 0.f, ay = 0.f;
    for (int i = start + half; i < end; i += 8) {
        float lam = 1.0f - Hent[i] * invMax;
        unsigned u = H2[(size_t)i*32 + l];
        ax += lam * bflo(u);
        ay += lam * bfhi(u);
    }
    partial[half][2*l]   = ax;
    partial[half][2*l+1] = ay;
    __syncthreads();
    if (tid < HDIM) {
        float s = 0.f;
        #pragma unroll
        for (int hh = 0; hh < 8; ++hh) s += partial[hh][tid];
        pooled[tid] = s;
    }
    __syncthreads();
    if (tid < CDIM) {
        float s = bc[tid];
        for (int k = 0; k < HDIM; ++k) s += pooled[k] * Wc[k*CDIM + tid];
        out[g*CDIM + tid] = s;
    }
}

extern "C" void kernel_launch(void* const* d_in, const int* in_sizes, int n_in,
                              void* d_out, int out_size, void* d_ws, size_t ws_size,
                              hipStream_t stream) {
    const float* feat  = (const float*)d_in[0];
    const int*   src   = (const int*)d_in[1];
    const int*   dst   = (const int*)d_in[2];
    const int*   n2g   = (const int*)d_in[3];
    const float* Ws    = (const float*)d_in[4];
    const float* bs    = (const float*)d_in[5];
    const float* gam   = (const float*)d_in[6];
    const float* bet   = (const float*)d_in[7];
    const float* mea   = (const float*)d_in[8];
    const float* var_  = (const float*)d_in[9];
    const float* Wc    = (const float*)d_in[10];
    const float* bc    = (const float*)d_in[11];
    float* out = (float*)d_out;

    char* ws = (char*)d_ws;
    size_t off = 0;
    auto take = [&](size_t bytes) {
        char* p = ws + off;
        off += (bytes + 255) & ~(size_t)255;
        return p;
    };

    unsigned* gcur     = (unsigned*)take((size_t)NBINS*GCUR_STRIDE*4);
    unsigned* ovfcnt   = (unsigned*)take(4);
    unsigned* maxH     = (unsigned*)take(4);
    int*      ovf      = (int*)take((size_t)OVFCAP*2*4);
    float*    Hent     = (float*)take((size_t)NNODES*4);
    unsigned* featb    = (unsigned*)take((size_t)NNODES*HDIM*2);
    unsigned* HA       = (unsigned*)take((size_t)NNODES*HDIM*2);
    unsigned* HB       = (unsigned*)take((size_t)NNODES*HDIM*2);
    unsigned* bin_edges= (unsigned*)take((size_t)NBINS*BINCAP*4);
    unsigned* cnt      = (unsigned*)take((size_t)NNODES*4);
    int*      csr      = (int*)take((size_t)NBINS*128*CAP*4);  // padded past NNODES

    hipMemsetAsync(gcur, 0, (size_t)NBINS*GCUR_STRIDE*4, stream);
    hipMemsetAsync(ovfcnt, 0, 4, stream);
    hipMemsetAsync(maxH, 0, 4, stream);

    prep<<<NEDGES/256, 256, 0, stream>>>((const float4*)feat, (uint4*)featb,
                                         src, dst, gcur, bin_edges, ovfcnt, ovf);
    build_csr<<<NBINS, 256, 0, stream>>>(gcur, bin_edges, cnt, csr, ovfcnt, ovf);

    int grid = (NNODES + TN - 1) / TN;
    layer_fused<<<grid, 256, 0, stream>>>(featb, cnt, csr, ovfcnt, ovf,
                                          Ws, bs, gam, bet, mea, var_, 0, (unsigned short*)HA);
    layer_fused<<<grid, 256, 0, stream>>>((const unsigned*)HA, cnt, csr, ovfcnt, ovf,
                                          Ws, bs, gam, bet, mea, var_, 1, (unsigned short*)HB);
    layer_fused<<<grid, 256, 0, stream>>>((const unsigned*)HB, cnt, csr, ovfcnt, ovf,
                                          Ws, bs, gam, bet, mea, var_, 2, (unsigned short*)HA);

    classify_bf16<<<(NNODES+31)/32, 256, 0, stream>>>((const uint4*)HA, Wc, bc, Hent, maxH);
    pool_final_bf16<<<NGRAPH, 256, 0, stream>>>(HA, Hent, maxH, n2g, Wc, bc, out);
}